// Round 6
// baseline (390.819 us; speedup 1.0000x reference)
//
#include <hip/hip_runtime.h>
#include <math.h>

#define L_SEQ 384
#define E_DIM 512
#define NHEAD 8
#define NBH   16
#define HD    64
#define JSPLIT 12
#define JTILE  32          // L_SEQ / JSPLIT
#define PROJ_ELEMS (NBH * L_SEQ * HD)   // 393216

typedef __attribute__((ext_vector_type(8))) __bf16 bf16x8;
typedef __attribute__((ext_vector_type(4))) float f32x4;

__device__ __forceinline__ float uniform_f(float v) {
  return __uint_as_float(__builtin_amdgcn_readfirstlane(__float_as_uint(v)));
}

__device__ __forceinline__ unsigned f2bf(float f) {   // RNE float->bf16 bits
  unsigned u = __float_as_uint(f);
  return (u + 0x7FFFu + ((u >> 16) & 1u)) >> 16;
}

__device__ __forceinline__ bf16x8 cvt8(float4 a, float4 b) {  // 8 fp32 -> bf16x8
  union { bf16x8 v; unsigned u[4]; } r;
  r.u[0] = f2bf(a.x) | (f2bf(a.y) << 16);
  r.u[1] = f2bf(a.z) | (f2bf(a.w) << 16);
  r.u[2] = f2bf(b.x) | (f2bf(b.y) << 16);
  r.u[3] = f2bf(b.z) | (f2bf(b.w) << 16);
  return r.v;
}

// sum over the 4 lanes of each quad — pure-VALU DPP quad_perm butterfly
__device__ __forceinline__ float quad_sum(float x) {
  x += __int_as_float(__builtin_amdgcn_mov_dpp(__float_as_int(x), 0xB1, 0xF, 0xF, 0)); // xor 1
  x += __int_as_float(__builtin_amdgcn_mov_dpp(__float_as_int(x), 0x4E, 0xF, 0xF, 0)); // xor 2
  return x;
}

// ---------------------------------------------------------------------------
// bf16 MFMA GEMM with in-register fp32->bf16 conversion of the inputs
// (kills the separate convert kernel: inputs are L2-resident, ~2 us of VALU).
// C = A @ B^T. A: MxK row-major (fp32, or bf16 if abf!=0), Bm: NxK fp32.
// Block 256 = 4 waves; tile 64(m)x64(n); wave = 16-row m-strip, 4 n-tiles.
// mode 0: C[m*N+f]; mode 1: head-scatter C[((b*8+h)*L+l)*64+d].
// Block (0,0,0) also zeroes the 192 berry group-counters (cnt != nullptr) —
// stream order guarantees this completes before berry launches.
// ---------------------------------------------------------------------------
__global__ __launch_bounds__(256) void gemm_mfma(
    const void* __restrict__ Av, const float* __restrict__ B0,
    const float* __restrict__ B1, const float* __restrict__ B2,
    float* __restrict__ C0, float* __restrict__ C1, float* __restrict__ C2,
    unsigned* __restrict__ cnt, int M, int N, int K, int mode, int abf)
{
  if (cnt && blockIdx.x == 0 && blockIdx.y == 0 && blockIdx.z == 0 &&
      threadIdx.x < 192)
    cnt[threadIdx.x] = 0u;

  const int z = blockIdx.z;
  const float* Bm = (z == 0) ? B0 : (z == 1) ? B1 : B2;
  float* Cp = (z == 0) ? C0 : (z == 1) ? C1 : C2;

  const int tid = threadIdx.x;
  const int wave = tid >> 6, lane = tid & 63;
  const int m0 = blockIdx.y * 64 + wave * 16;
  const int n0 = blockIdx.x * 64;
  const int mr = lane & 15, quad = lane >> 4;

  f32x4 acc[4];
  #pragma unroll
  for (int nt = 0; nt < 4; ++nt) acc[nt] = (f32x4){0.f, 0.f, 0.f, 0.f};

  const float* apf = (const float*)Av + (size_t)(m0 + mr) * K + quad * 8;
  const __bf16* apb = (const __bf16*)Av + (size_t)(m0 + mr) * K + quad * 8;
  const float* bp = Bm + (size_t)(n0 + mr) * K + quad * 8;

  #pragma unroll 2
  for (int k0 = 0; k0 < K; k0 += 32) {
    bf16x8 a;
    if (abf) {
      a = *(const bf16x8*)(apb + k0);
    } else {
      float4 a0 = *(const float4*)(apf + k0);
      float4 a1 = *(const float4*)(apf + k0 + 4);
      a = cvt8(a0, a1);
    }
    #pragma unroll
    for (int nt = 0; nt < 4; ++nt) {
      const float* bq = bp + (size_t)nt * 16 * K + k0;
      float4 b0 = *(const float4*)(bq);
      float4 b1 = *(const float4*)(bq + 4);
      bf16x8 b = cvt8(b0, b1);
      acc[nt] = __builtin_amdgcn_mfma_f32_16x16x32_bf16(a, b, acc[nt], 0, 0, 0);
    }
  }

  #pragma unroll
  for (int nt = 0; nt < 4; ++nt) {
    int n = n0 + nt * 16 + mr;
    #pragma unroll
    for (int r = 0; r < 4; ++r) {
      int m = m0 + quad * 4 + r;
      if (mode == 0) {
        Cp[(size_t)m * N + n] = acc[nt][r];
      } else {
        int b = m / L_SEQ, l = m % L_SEQ;
        int h = n >> 6, d = n & 63;
        Cp[((size_t)(b * NHEAD + h) * L_SEQ + l) * HD + d] = acc[nt][r];
      }
    }
  }
}

// ---------------------------------------------------------------------------
// Fused pairwise core v6 = v5 + in-kernel slab reduction (last-block-done).
// Block 128 = 32 i x 4 lanes, 4 atoms/thread; grid (12, 12, 16).
// After slab store: release fence -> device atomicAdd on group counter;
// the 12th block of each (bh, i-tile) group sums the 12 slabs and emits
// bf16 ctx in (b,l,e) layout for the output GEMM. Kills the reduce node.
// ---------------------------------------------------------------------------
__global__ __launch_bounds__(128, 4) void berry_main(
    const float* __restrict__ Q, const float* __restrict__ K,
    const float* __restrict__ V, const float* __restrict__ dde_w,
    const float* __restrict__ dde_b, float* __restrict__ CTXS,
    unsigned short* __restrict__ CTXB, unsigned* __restrict__ cnt)
{
  __shared__ float kt[JTILE][HD];   // normalized k atoms
  __shared__ float vt[JTILE][HD];   // raw v
  __shared__ unsigned last;

  const int tid = threadIdx.x;
  const int bh = blockIdx.z;
  const int i = blockIdx.y * 32 + (tid >> 2);
  const int ag = tid & 3;                 // lane-in-quad: atoms ag*4 .. ag*4+3
  const int js = blockIdx.x;
  const int j0 = js * JTILE;

  // gate params in SGPRs; mean over 16 atoms folded into weights
  float gw[16];
  #pragma unroll
  for (int t = 0; t < 16; ++t) gw[t] = uniform_f(dde_w[t]) * 0.0625f;
  const float gb0 = uniform_f(dde_b[0]), gb1 = uniform_f(dde_b[1]);
  const float gb2 = uniform_f(dde_b[2]), gb3 = uniform_f(dde_b[3]);

  float4 qa[4], ctx[4];
  const float* qp = Q + ((size_t)(bh * L_SEQ + i) * HD + ag * 16);
  #pragma unroll
  for (int t = 0; t < 4; ++t) {
    float4 q = ((const float4*)qp)[t];
    float d = q.x * q.x + q.y * q.y + q.z * q.z + q.w * q.w;
    float r = __builtin_amdgcn_rsqf(fmaxf(d, 1e-30f));
    qa[t].x = q.x * r; qa[t].y = q.y * r; qa[t].z = q.z * r; qa[t].w = q.w * r;
    ctx[t] = make_float4(0.f, 0.f, 0.f, 0.f);
  }

  // stage K (normalized per atom) + V: 32 j x 16 atoms = 512, 4/thread
  #pragma unroll
  for (int p = 0; p < 4; ++p) {
    int idx = tid + p * 128;
    int jj = idx >> 4, at = idx & 15;
    size_t g = (size_t)(bh * L_SEQ + j0 + jj) * HD + at * 4;
    float4 kq = *(const float4*)(K + g);
    float d = kq.x * kq.x + kq.y * kq.y + kq.z * kq.z + kq.w * kq.w;
    float r = __builtin_amdgcn_rsqf(fmaxf(d, 1e-30f));
    kq.x *= r; kq.y *= r; kq.z *= r; kq.w *= r;
    *(float4*)&kt[jj][at * 4] = kq;
    *(float4*)&vt[jj][at * 4] = *(const float4*)(V + g);
  }
  __syncthreads();

  for (int jj = 0; jj < JTILE; ++jj) {
    float4 h[4];
    float gsx = 0.f, gsy = 0.f, gsz = 0.f, gsw = 0.f;
    #pragma unroll
    for (int a = 0; a < 4; ++a) {
      float4 kq = *(const float4*)&kt[jj][ag * 16 + a * 4];
      h[a].x = qa[a].x * kq.x - qa[a].y * kq.y - qa[a].z * kq.z - qa[a].w * kq.w;
      h[a].y = qa[a].x * kq.y + qa[a].y * kq.x + qa[a].z * kq.w - qa[a].w * kq.z;
      h[a].z = qa[a].x * kq.z - qa[a].y * kq.w + qa[a].z * kq.x + qa[a].w * kq.y;
      h[a].w = qa[a].x * kq.w + qa[a].y * kq.z - qa[a].z * kq.y + qa[a].w * kq.x;
      gsx += h[a].x; gsy += h[a].y; gsz += h[a].z; gsw += h[a].w;
    }
    gsx = quad_sum(gsx); gsy = quad_sum(gsy);
    gsz = quad_sum(gsz); gsw = quad_sum(gsw);

    float t0 = gb0 + gw[0]  * gsx + gw[1]  * gsy + gw[2]  * gsz + gw[3]  * gsw;
    float t1 = gb1 + gw[4]  * gsx + gw[5]  * gsy + gw[6]  * gsz + gw[7]  * gsw;
    float t2 = gb2 + gw[8]  * gsx + gw[9]  * gsy + gw[10] * gsz + gw[11] * gsw;
    float t3 = gb3 + gw[12] * gsx + gw[13] * gsy + gw[14] * gsz + gw[15] * gsw;
    float4 g;
    g.x = __builtin_amdgcn_rcpf(1.f + __expf(-t0));
    g.y = __builtin_amdgcn_rcpf(1.f + __expf(-t1));
    g.z = __builtin_amdgcn_rcpf(1.f + __expf(-t2));
    g.w = __builtin_amdgcn_rcpf(1.f + __expf(-t3));

    #pragma unroll
    for (int a = 0; a < 4; ++a) {
      float4 vq = *(const float4*)&vt[jj][ag * 16 + a * 4];
      float sx = h[a].x * g.x, sy = h[a].y * g.y;
      float sz = h[a].z * g.z, sw = h[a].w * g.w;
      ctx[a].x += sx * vq.x - sy * vq.y - sz * vq.z - sw * vq.w;
      ctx[a].y += sx * vq.y + sy * vq.x + sz * vq.w - sw * vq.z;
      ctx[a].z += sx * vq.z - sy * vq.w + sz * vq.x + sw * vq.y;
      ctx[a].w += sx * vq.w + sy * vq.z - sz * vq.y + sw * vq.x;
    }
  }

  // slab store for this j-chunk
  float* cp = CTXS + ((size_t)(js * NBH + bh) * L_SEQ + i) * HD + ag * 16;
  #pragma unroll
  for (int t = 0; t < 4; ++t) ((float4*)cp)[t] = ctx[t];

  // ---- last-block-done slab reduction (release/acquire across XCDs) ----
  __threadfence();                       // release: flush slab stores
  __syncthreads();                       // order all threads' fences
  if (tid == 0)
    last = atomicAdd(&cnt[bh * 12 + blockIdx.y], 1u);   // device-scope
  __syncthreads();
  if (last == JSPLIT - 1) {
    __threadfence();                     // acquire: see other blocks' slabs
    const int r = tid >> 2;              // 0..31 row in this i-tile
    const int c0 = (tid & 3) * 16;       // 16 floats
    const size_t rowoff = ((size_t)(bh * L_SEQ) + blockIdx.y * 32 + r) * HD + c0;
    float4 s[4];
    #pragma unroll
    for (int t = 0; t < 4; ++t) s[t] = make_float4(0.f, 0.f, 0.f, 0.f);
    for (int j2 = 0; j2 < JSPLIT; ++j2) {
      const float* src = CTXS + (size_t)j2 * PROJ_ELEMS + rowoff;
      #pragma unroll
      for (int t = 0; t < 4; ++t) {
        float4 v = ((const float4*)src)[t];
        s[t].x += v.x; s[t].y += v.y; s[t].z += v.z; s[t].w += v.w;
      }
    }
    const int b = bh >> 3, hh = bh & 7;
    const int irow = blockIdx.y * 32 + r;
    unsigned short* dst = CTXB + ((size_t)(b * L_SEQ + irow) * E_DIM) + hh * HD + c0;
    #pragma unroll
    for (int t = 0; t < 4; ++t) {
      unsigned lo = f2bf(s[t].x) | (f2bf(s[t].y) << 16);
      unsigned hi = f2bf(s[t].z) | (f2bf(s[t].w) << 16);
      *(uint2*)(dst + t * 4) = make_uint2(lo, hi);
    }
  }
}

// ---------------------------------------------------------------------------
// Workspace (24,380,160 B < proven 25.2 MB):
//   [0        .. 1572864)   Qw fp32
//   [1572864  .. 3145728)   Kw fp32
//   [3145728  .. 4718592)   Vw fp32
//   [4718592  .. 23592960)  CTXS fp32 (12 slabs)
//   [23592960 .. 24379392)  CTXB bf16 (reduced ctx, (b,l,e))
//   [24379392 .. 24380160)  cnt (192 u32, zeroed by proj GEMM block 0)
// ---------------------------------------------------------------------------
extern "C" void kernel_launch(void* const* d_in, const int* in_sizes, int n_in,
                              void* d_out, int out_size, void* d_ws, size_t ws_size,
                              hipStream_t stream)
{
  const float* x     = (const float*)d_in[0];
  const float* Wq    = (const float*)d_in[1];
  const float* Wk    = (const float*)d_in[2];
  const float* Wv    = (const float*)d_in[3];
  const float* Wo    = (const float*)d_in[4];
  const float* dde_w = (const float*)d_in[5];
  const float* dde_b = (const float*)d_in[6];
  float* out = (float*)d_out;

  char* ws = (char*)d_ws;
  float* Qw            = (float*)(ws + 0);
  float* Kw            = (float*)(ws + 1572864);
  float* Vw            = (float*)(ws + 3145728);
  float* CTXS          = (float*)(ws + 4718592);
  unsigned short* CTXB = (unsigned short*)(ws + 23592960);
  unsigned*       cnt  = (unsigned*)(ws + 24379392);

  // 1) Q/K/V projections (fp32 in, convert-in-register, MFMA) + zero counters
  gemm_mfma<<<dim3(8, 12, 3), 256, 0, stream>>>(
      x, Wq, Wk, Wv, Qw, Kw, Vw, cnt, 2 * L_SEQ, E_DIM, E_DIM, 1, 0);

  // 2) fused pairwise core + in-kernel slab reduction -> bf16 ctx
  berry_main<<<dim3(JSPLIT, 12, NBH), 128, 0, stream>>>(
      Qw, Kw, Vw, dde_w, dde_b, CTXS, CTXB, cnt);

  // 3) output projection (A = bf16 ctx, B = Wo fp32 convert-in-register)
  gemm_mfma<<<dim3(8, 12, 1), 256, 0, stream>>>(
      CTXB, Wo, nullptr, nullptr, out, nullptr, nullptr, nullptr,
      2 * L_SEQ, E_DIM, E_DIM, 0, 1);
}

// Round 7
// 201.879 us; speedup vs baseline: 1.9359x; 1.9359x over previous
//
#include <hip/hip_runtime.h>
#include <math.h>

#define L_SEQ 384
#define E_DIM 512
#define NHEAD 8
#define NBH   16
#define HD    64
#define JSPLIT 12
#define JTILE  32          // L_SEQ / JSPLIT
#define PROJ_ELEMS (NBH * L_SEQ * HD)   // 393216

typedef __attribute__((ext_vector_type(8))) __bf16 bf16x8;
typedef __attribute__((ext_vector_type(4))) float f32x4;

__device__ __forceinline__ float uniform_f(float v) {
  return __uint_as_float(__builtin_amdgcn_readfirstlane(__float_as_uint(v)));
}

__device__ __forceinline__ unsigned f2bf(float f) {   // RNE float->bf16 bits
  unsigned u = __float_as_uint(f);
  return (u + 0x7FFFu + ((u >> 16) & 1u)) >> 16;
}

__device__ __forceinline__ bf16x8 cvt8(float4 a, float4 b) {  // 8 fp32 -> bf16x8
  union { bf16x8 v; unsigned u[4]; } r;
  r.u[0] = f2bf(a.x) | (f2bf(a.y) << 16);
  r.u[1] = f2bf(a.z) | (f2bf(a.w) << 16);
  r.u[2] = f2bf(b.x) | (f2bf(b.y) << 16);
  r.u[3] = f2bf(b.z) | (f2bf(b.w) << 16);
  return r.v;
}

// sum over the 4 lanes of each quad — pure-VALU DPP quad_perm butterfly
__device__ __forceinline__ float quad_sum(float x) {
  x += __int_as_float(__builtin_amdgcn_mov_dpp(__float_as_int(x), 0xB1, 0xF, 0xF, 0)); // xor 1
  x += __int_as_float(__builtin_amdgcn_mov_dpp(__float_as_int(x), 0x4E, 0xF, 0xF, 0)); // xor 2
  return x;
}

// ---------------------------------------------------------------------------
// bf16 MFMA GEMM, fp32 inputs converted in-register. C = A @ B^T.
// Block 128 = 2 waves; tile 32(m)x64(n); wave = 16-row m-strip, 4 n-tiles.
// asum=0: A = plain fp32 MxK row-major.
// asum=1: A-frag = sum of JSPLIT ctx slabs (fp32, head-interleaved layout
//         slab[js][(b*8+h)*L + l][d] with k = h*64+d) — folds the slab
//         reduction into this GEMM; no fence needed (stream-ordered after
//         berry; round-6 lesson: per-block __threadfence = L2 writeback
//         disaster, 82.7 -> 318 us).
// mode 0: C[m*N+f]; mode 1: head-scatter C[((b*8+h)*L+l)*64+d].
// ---------------------------------------------------------------------------
__global__ __launch_bounds__(128) void gemm_mfma(
    const float* __restrict__ Av, const float* __restrict__ B0,
    const float* __restrict__ B1, const float* __restrict__ B2,
    float* __restrict__ C0, float* __restrict__ C1, float* __restrict__ C2,
    int M, int N, int K, int mode, int asum)
{
  const int z = blockIdx.z;
  const float* Bm = (z == 0) ? B0 : (z == 1) ? B1 : B2;
  float* Cp = (z == 0) ? C0 : (z == 1) ? C1 : C2;

  const int tid = threadIdx.x;
  const int wave = tid >> 6, lane = tid & 63;
  const int m0 = blockIdx.y * 32 + wave * 16;
  const int n0 = blockIdx.x * 64;
  const int mr = lane & 15, quad = lane >> 4;
  const int m = m0 + mr;

  f32x4 acc[4];
  #pragma unroll
  for (int nt = 0; nt < 4; ++nt) acc[nt] = (f32x4){0.f, 0.f, 0.f, 0.f};

  const float* bp = Bm + (size_t)(n0 + mr) * K + quad * 8;
  const float* apf = Av + (size_t)m * K + quad * 8;        // asum=0 path
  const int bb = m / L_SEQ, l = m - bb * L_SEQ;            // asum=1 path
  const size_t rowA = ((size_t)(bb * NHEAD) * L_SEQ + l) * HD;

  for (int k0 = 0; k0 < K; k0 += 32) {
    bf16x8 a;
    if (!asum) {
      float4 a0 = *(const float4*)(apf + k0);
      float4 a1 = *(const float4*)(apf + k0 + 4);
      a = cvt8(a0, a1);
    } else {
      int k = k0 + quad * 8;
      int h = k >> 6, d = k & 63;
      const float* ap = Av + rowA + (size_t)h * (L_SEQ * HD) + d;
      float4 s0 = make_float4(0.f, 0.f, 0.f, 0.f);
      float4 s1 = make_float4(0.f, 0.f, 0.f, 0.f);
      #pragma unroll
      for (int js = 0; js < JSPLIT; ++js) {
        float4 v0 = *(const float4*)(ap + (size_t)js * PROJ_ELEMS);
        float4 v1 = *(const float4*)(ap + (size_t)js * PROJ_ELEMS + 4);
        s0.x += v0.x; s0.y += v0.y; s0.z += v0.z; s0.w += v0.w;
        s1.x += v1.x; s1.y += v1.y; s1.z += v1.z; s1.w += v1.w;
      }
      a = cvt8(s0, s1);
    }
    #pragma unroll
    for (int nt = 0; nt < 4; ++nt) {
      const float* bq = bp + (size_t)nt * 16 * K + k0;
      float4 b0 = *(const float4*)(bq);
      float4 b1 = *(const float4*)(bq + 4);
      bf16x8 b = cvt8(b0, b1);
      acc[nt] = __builtin_amdgcn_mfma_f32_16x16x32_bf16(a, b, acc[nt], 0, 0, 0);
    }
  }

  #pragma unroll
  for (int nt = 0; nt < 4; ++nt) {
    int n = n0 + nt * 16 + mr;
    #pragma unroll
    for (int r = 0; r < 4; ++r) {
      int mm = m0 + quad * 4 + r;
      if (mode == 0) {
        Cp[(size_t)mm * N + n] = acc[nt][r];
      } else {
        int b = mm / L_SEQ, ll = mm % L_SEQ;
        int h = n >> 6, d = n & 63;
        Cp[((size_t)(b * NHEAD + h) * L_SEQ + ll) * HD + d] = acc[nt][r];
      }
    }
  }
}

// ---------------------------------------------------------------------------
// Fused pairwise core (= round-5 proven version, 82.7 us).
// Block 128 = 32 i x 4 lanes, 4 atoms/thread; grid (12, 12, 16).
// Prenormalized q/k (|ham(q,k)|=|q||k|); gate reduce = DPP quad butterflies;
// plain slab stores, no fences, no atomics.
// ---------------------------------------------------------------------------
__global__ __launch_bounds__(128, 4) void berry_main(
    const float* __restrict__ Q, const float* __restrict__ K,
    const float* __restrict__ V, const float* __restrict__ dde_w,
    const float* __restrict__ dde_b, float* __restrict__ CTXS)
{
  __shared__ float kt[JTILE][HD];   // normalized k atoms
  __shared__ float vt[JTILE][HD];   // raw v

  const int tid = threadIdx.x;
  const int bh = blockIdx.z;
  const int i = blockIdx.y * 32 + (tid >> 2);
  const int ag = tid & 3;                 // lane-in-quad: atoms ag*4 .. ag*4+3
  const int js = blockIdx.x;
  const int j0 = js * JTILE;

  // gate params in SGPRs; mean over 16 atoms folded into weights
  float gw[16];
  #pragma unroll
  for (int t = 0; t < 16; ++t) gw[t] = uniform_f(dde_w[t]) * 0.0625f;
  const float gb0 = uniform_f(dde_b[0]), gb1 = uniform_f(dde_b[1]);
  const float gb2 = uniform_f(dde_b[2]), gb3 = uniform_f(dde_b[3]);

  float4 qa[4], ctx[4];
  const float* qp = Q + ((size_t)(bh * L_SEQ + i) * HD + ag * 16);
  #pragma unroll
  for (int t = 0; t < 4; ++t) {
    float4 q = ((const float4*)qp)[t];
    float d = q.x * q.x + q.y * q.y + q.z * q.z + q.w * q.w;
    float r = __builtin_amdgcn_rsqf(fmaxf(d, 1e-30f));
    qa[t].x = q.x * r; qa[t].y = q.y * r; qa[t].z = q.z * r; qa[t].w = q.w * r;
    ctx[t] = make_float4(0.f, 0.f, 0.f, 0.f);
  }

  // stage K (normalized per atom) + V: 32 j x 16 atoms = 512, 4/thread
  #pragma unroll
  for (int p = 0; p < 4; ++p) {
    int idx = tid + p * 128;
    int jj = idx >> 4, at = idx & 15;
    size_t g = (size_t)(bh * L_SEQ + j0 + jj) * HD + at * 4;
    float4 kq = *(const float4*)(K + g);
    float d = kq.x * kq.x + kq.y * kq.y + kq.z * kq.z + kq.w * kq.w;
    float r = __builtin_amdgcn_rsqf(fmaxf(d, 1e-30f));
    kq.x *= r; kq.y *= r; kq.z *= r; kq.w *= r;
    *(float4*)&kt[jj][at * 4] = kq;
    *(float4*)&vt[jj][at * 4] = *(const float4*)(V + g);
  }
  __syncthreads();

  for (int jj = 0; jj < JTILE; ++jj) {
    float4 h[4];
    float gsx = 0.f, gsy = 0.f, gsz = 0.f, gsw = 0.f;
    #pragma unroll
    for (int a = 0; a < 4; ++a) {
      float4 kq = *(const float4*)&kt[jj][ag * 16 + a * 4];
      h[a].x = qa[a].x * kq.x - qa[a].y * kq.y - qa[a].z * kq.z - qa[a].w * kq.w;
      h[a].y = qa[a].x * kq.y + qa[a].y * kq.x + qa[a].z * kq.w - qa[a].w * kq.z;
      h[a].z = qa[a].x * kq.z - qa[a].y * kq.w + qa[a].z * kq.x + qa[a].w * kq.y;
      h[a].w = qa[a].x * kq.w + qa[a].y * kq.z - qa[a].z * kq.y + qa[a].w * kq.x;
      gsx += h[a].x; gsy += h[a].y; gsz += h[a].z; gsw += h[a].w;
    }
    gsx = quad_sum(gsx); gsy = quad_sum(gsy);
    gsz = quad_sum(gsz); gsw = quad_sum(gsw);

    float t0 = gb0 + gw[0]  * gsx + gw[1]  * gsy + gw[2]  * gsz + gw[3]  * gsw;
    float t1 = gb1 + gw[4]  * gsx + gw[5]  * gsy + gw[6]  * gsz + gw[7]  * gsw;
    float t2 = gb2 + gw[8]  * gsx + gw[9]  * gsy + gw[10] * gsz + gw[11] * gsw;
    float t3 = gb3 + gw[12] * gsx + gw[13] * gsy + gw[14] * gsz + gw[15] * gsw;
    float4 g;
    g.x = __builtin_amdgcn_rcpf(1.f + __expf(-t0));
    g.y = __builtin_amdgcn_rcpf(1.f + __expf(-t1));
    g.z = __builtin_amdgcn_rcpf(1.f + __expf(-t2));
    g.w = __builtin_amdgcn_rcpf(1.f + __expf(-t3));

    #pragma unroll
    for (int a = 0; a < 4; ++a) {
      float4 vq = *(const float4*)&vt[jj][ag * 16 + a * 4];
      float sx = h[a].x * g.x, sy = h[a].y * g.y;
      float sz = h[a].z * g.z, sw = h[a].w * g.w;
      ctx[a].x += sx * vq.x - sy * vq.y - sz * vq.z - sw * vq.w;
      ctx[a].y += sx * vq.y + sy * vq.x + sz * vq.w - sw * vq.z;
      ctx[a].z += sx * vq.z - sy * vq.w + sz * vq.x + sw * vq.y;
      ctx[a].w += sx * vq.w + sy * vq.z - sz * vq.y + sw * vq.x;
    }
  }

  // plain stores into this j-chunk's slab
  float* cp = CTXS + ((size_t)(js * NBH + bh) * L_SEQ + i) * HD + ag * 16;
  #pragma unroll
  for (int t = 0; t < 4; ++t) ((float4*)cp)[t] = ctx[t];
}

// ---------------------------------------------------------------------------
// Workspace (23,592,960 B):
//   [0        .. 1572864)   Qw fp32
//   [1572864  .. 3145728)   Kw fp32
//   [3145728  .. 4718592)   Vw fp32
//   [4718592  .. 23592960)  CTXS fp32 (12 slabs; reduced inline by out-GEMM)
// ---------------------------------------------------------------------------
extern "C" void kernel_launch(void* const* d_in, const int* in_sizes, int n_in,
                              void* d_out, int out_size, void* d_ws, size_t ws_size,
                              hipStream_t stream)
{
  const float* x     = (const float*)d_in[0];
  const float* Wq    = (const float*)d_in[1];
  const float* Wk    = (const float*)d_in[2];
  const float* Wv    = (const float*)d_in[3];
  const float* Wo    = (const float*)d_in[4];
  const float* dde_w = (const float*)d_in[5];
  const float* dde_b = (const float*)d_in[6];
  float* out = (float*)d_out;

  char* ws = (char*)d_ws;
  float* Qw   = (float*)(ws + 0);
  float* Kw   = (float*)(ws + 1572864);
  float* Vw   = (float*)(ws + 3145728);
  float* CTXS = (float*)(ws + 4718592);

  // 1) Q/K/V projections (fp32 in, convert-in-register, MFMA), head-scatter
  gemm_mfma<<<dim3(8, 24, 3), 128, 0, stream>>>(
      x, Wq, Wk, Wv, Qw, Kw, Vw, 2 * L_SEQ, E_DIM, E_DIM, 1, 0);

  // 2) fused pairwise core -> 12 fp32 slabs
  berry_main<<<dim3(JSPLIT, 12, NBH), 128, 0, stream>>>(
      Qw, Kw, Vw, dde_w, dde_b, CTXS);

  // 3) output projection; A-fragments = inline 12-slab sum (L2-resident)
  gemm_mfma<<<dim3(8, 24, 1), 128, 0, stream>>>(
      CTXS, Wo, nullptr, nullptr, out, nullptr, nullptr,
      2 * L_SEQ, E_DIM, E_DIM, 0, 1);
}